// Round 13
// baseline (435.023 us; speedup 1.0000x reference)
//
#include <hip/hip_runtime.h>
#include <math.h>

#define BATCH 8
#define CCH 20
#define THW 15000
#define HW 625
#define SSIDE 25

#define NKEY 15000
#define TPAD 15104      // 59*256, padded key dim
#define NKT 118         // ceil(15000/128) k-tiles of 128
#define NKC 15          // k-chunks (8 tiles each, last gets 6)

typedef __attribute__((ext_vector_type(8))) short bf16x8;
typedef __attribute__((ext_vector_type(4))) float f32x4;

// ---- ws layout (byte offsets) ----
#define YBF_OFF  0ULL
#define XA_OFF   640000ULL
#define XB_OFF   5760000ULL
#define WT0_OFF  10880000ULL
#define WT_OFF   11469824ULL
#define FMT_OFF  5760000ULL
#define FM32_OFF 13493248ULL
#define FQB_OFF  21226496ULL
#define PART_OFF XA_OFF   // bf16 partials: 8*5*15*128*48 B = 3.69 MB < 5.12 MB

__device__ __forceinline__ ushort f2bf(float x) {
    unsigned u = __float_as_uint(x);
    u = (u + 0x7FFFu + ((u >> 16) & 1u)) >> 16;
    return (ushort)u;
}
__device__ __forceinline__ float bf2f(ushort v) {
    return __uint_as_float(((unsigned)v) << 16);
}

// ===== prep: fm -> fmbT (t-major rows of 32 ch) + fmb32 (ch-major), bf16 =====
__global__ __launch_bounds__(256) void prep_fm(const float* __restrict__ fm,
                                               ushort* __restrict__ fmbT,
                                               ushort* __restrict__ fmb32) {
    __shared__ ushort sT2[256][34];
    const int tid = threadIdx.x;
    const int t0 = blockIdx.x * 256;
    const int b = blockIdx.y;
    const int t = t0 + tid;
    #pragma unroll 4
    for (int c = 0; c < CCH; c++) {
        float v = (t < NKEY) ? fm[((size_t)b * CCH + c) * THW + t] : 0.f;
        ushort h = f2bf(v);
        sT2[tid][c] = h;
        fmb32[((size_t)b * 32 + c) * TPAD + t] = h;
    }
    __syncthreads();
    const int g = tid >> 4, j = tid & 15;
    uint* dstb = (uint*)fmbT + ((size_t)b * TPAD + t0) * 16 + j;
    #pragma unroll
    for (int i = 0; i < 16; i++) {
        int r = g + 16 * i;
        uint v = 0;
        if (j < 10) v = *(const uint*)&sT2[r][2 * j];
        dstb[(size_t)r * 16] = v;
    }
}

// zero fmb32 channel rows 20..31
__global__ __launch_bounds__(256) void prep_fmz(ushort* __restrict__ fmb32) {
    int idx = blockIdx.x * 256 + threadIdx.x;
    if (idx >= 181248) return;             // 8*12*1888
    int t8 = idx % 1888;
    int rest = idx / 1888;
    int cz = rest % 12, b = rest / 12;
    uint4 z = make_uint4(0, 0, 0, 0);
    *(uint4*)(fmb32 + ((size_t)(b * 32 + 20 + cz)) * TPAD + t8 * 8) = z;
}

// fq -> fqb bf16 [b][640][32], scale 1/sqrt(512)*log2(e) folded
__global__ __launch_bounds__(256) void prep_fq(const float* __restrict__ fq,
                                               ushort* __restrict__ fqb) {
    int idx = blockIdx.x * 256 + threadIdx.x;
    if (idx >= BATCH * 640) return;
    int b = idx / 640, q = idx % 640;
    const float qscale = 1.4426950408889634f * 0.04419417382415922f;
    ushort* dst = fqb + (size_t)idx * 32;
    #pragma unroll 4
    for (int c = 0; c < CCH; c++) {
        float v = (q < HW) ? fq[((size_t)b * CCH + c) * HW + q] * qscale : 0.f;
        dst[c] = f2bf(v);
    }
    #pragma unroll
    for (int c = CCH; c < 32; c++) dst[c] = 0;
}

// ===== MFMA flash attention, 512-thread blocks (R12 version, unchanged) =====
__global__ __launch_bounds__(512) void attn_flash(const ushort* __restrict__ fmbT,
                                                  const ushort* __restrict__ fmb32,
                                                  const ushort* __restrict__ fqb,
                                                  char* __restrict__ part) {
    __shared__ __align__(16) ushort sP[8][2][16][136];
    const int tid = threadIdx.x;
    const int wave = tid >> 6, lane = tid & 63;
    const int q16 = lane & 15, quad = lane >> 4;
    const int qt = blockIdx.x * 2 + (wave >> 2);
    const int wq = wave & 3;
    const int kc = blockIdx.y, b = blockIdx.z;
    if (qt >= 5) return;

    bf16x8 Qf[2];
    #pragma unroll
    for (int nf = 0; nf < 2; nf++)
        Qf[nf] = *(const bf16x8*)(fqb + ((size_t)(b * 640 + qt * 128 + wq * 32 + nf * 16 + q16) << 5) + quad * 8);

    f32x4 O[2][2];
    #pragma unroll
    for (int nf = 0; nf < 2; nf++) { O[nf][0] = (f32x4)0.f; O[nf][1] = (f32x4)0.f; }
    float lp0 = 0.f, lp1 = 0.f;
    const f32x4 zz = (f32x4)0.f;

    const int kt0 = kc * 8;
    const int kt1 = (kt0 + 8 < NKT) ? kt0 + 8 : NKT;

    for (int kt = kt0; kt < kt1; kt++) {
        const int t0 = kt << 7;
        const bool tail = (t0 + 128 > NKEY);
        bf16x8 Ak[8], Av[8];
        #pragma unroll
        for (int m = 0; m < 8; m++)
            Ak[m] = *(const bf16x8*)(fmbT + ((size_t)(b * TPAD + t0 + m * 16 + q16) << 5) + quad * 8);
        #pragma unroll
        for (int mp = 0; mp < 4; mp++)
            #pragma unroll
            for (int cf = 0; cf < 2; cf++)
                Av[mp * 2 + cf] = *(const bf16x8*)(fmb32 + (size_t)(b * 32 + cf * 16 + q16) * TPAD + t0 + mp * 32 + quad * 8);

        f32x4 S[8][2];
        #pragma unroll
        for (int m = 0; m < 8; m++) {
            S[m][0] = __builtin_amdgcn_mfma_f32_16x16x32_bf16(Ak[m], Qf[0], zz, 0, 0, 0);
            S[m][1] = __builtin_amdgcn_mfma_f32_16x16x32_bf16(Ak[m], Qf[1], zz, 0, 0, 0);
        }

        #pragma unroll
        for (int nf = 0; nf < 2; nf++) {
            float lacc = 0.f;
            #pragma unroll
            for (int m = 0; m < 8; m++) {
                float p[4];
                #pragma unroll
                for (int i = 0; i < 4; i++) {
                    float v = __builtin_amdgcn_exp2f(S[m][nf][i]);
                    if (tail && (t0 + m * 16 + quad * 4 + i >= NKEY)) v = 0.f;
                    p[i] = v;
                }
                lacc += (p[0] + p[1]) + (p[2] + p[3]);
                uint pk0 = __builtin_amdgcn_perm(__float_as_uint(p[1]) + 0x8000u,
                                                 __float_as_uint(p[0]) + 0x8000u, 0x07060302u);
                uint pk1 = __builtin_amdgcn_perm(__float_as_uint(p[3]) + 0x8000u,
                                                 __float_as_uint(p[2]) + 0x8000u, 0x07060302u);
                uint* dst = (uint*)&sP[wave][nf][q16][m * 16 + quad * 4];
                dst[0] = pk0;
                dst[1] = pk1;
            }
            if (nf == 0) lp0 += lacc; else lp1 += lacc;
        }

        #pragma unroll
        for (int mp = 0; mp < 4; mp++) {
            bf16x8 Bp0 = *(const bf16x8*)&sP[wave][0][q16][mp * 32 + quad * 8];
            bf16x8 Bp1 = *(const bf16x8*)&sP[wave][1][q16][mp * 32 + quad * 8];
            O[0][0] = __builtin_amdgcn_mfma_f32_16x16x32_bf16(Av[mp * 2 + 0], Bp0, O[0][0], 0, 0, 0);
            O[0][1] = __builtin_amdgcn_mfma_f32_16x16x32_bf16(Av[mp * 2 + 1], Bp0, O[0][1], 0, 0, 0);
            O[1][0] = __builtin_amdgcn_mfma_f32_16x16x32_bf16(Av[mp * 2 + 0], Bp1, O[1][0], 0, 0, 0);
            O[1][1] = __builtin_amdgcn_mfma_f32_16x16x32_bf16(Av[mp * 2 + 1], Bp1, O[1][1], 0, 0, 0);
        }
    }

    lp0 += __shfl_xor(lp0, 16); lp0 += __shfl_xor(lp0, 32);
    lp1 += __shfl_xor(lp1, 16); lp1 += __shfl_xor(lp1, 32);

    #pragma unroll
    for (int nf = 0; nf < 2; nf++) {
        int ql = wq * 32 + nf * 16 + q16;
        size_t rec = ((((size_t)b * 5 + qt) * NKC + kc) * 128 + ql) * 48;
        uint2 pk;
        pk.x = (unsigned)f2bf(O[nf][0][0]) | ((unsigned)f2bf(O[nf][0][1]) << 16);
        pk.y = (unsigned)f2bf(O[nf][0][2]) | ((unsigned)f2bf(O[nf][0][3]) << 16);
        *(uint2*)(part + rec + quad * 8) = pk;
        if (quad == 0) {
            uint2 pk1;
            pk1.x = (unsigned)f2bf(O[nf][1][0]) | ((unsigned)f2bf(O[nf][1][1]) << 16);
            pk1.y = (unsigned)f2bf(O[nf][1][2]) | ((unsigned)f2bf(O[nf][1][3]) << 16);
            *(uint2*)(part + rec + 32) = pk1;
            *(float*)(part + rec + 40) = (nf == 0) ? lp0 : lp1;
        }
    }
}

// merge partials -> YBF bf16 NHWC [b][625][64]
__global__ __launch_bounds__(256) void attn_merge(const char* __restrict__ part,
                                                  const float* __restrict__ fq,
                                                  ushort* __restrict__ ybf) {
    int g = blockIdx.x * 256 + threadIdx.x;
    if (g >= BATCH * HW) return;
    int b = g / HW, q = g % HW;
    int qt = q >> 7, ql = q & 127;
    const char* pb = part + ((((size_t)b * 5 + qt) * NKC) * 128 + ql) * 48;
    float L = 0.f;
    float acc[CCH];
    #pragma unroll
    for (int c = 0; c < CCH; c++) acc[c] = 0.f;
    for (int kc = 0; kc < NKC; kc++) {
        const char* rec = pb + (size_t)kc * 128 * 48;
        L += *(const float*)(rec + 40);
        const ushort* av = (const ushort*)rec;
        #pragma unroll
        for (int c = 0; c < CCH; c++) acc[c] += bf2f(av[c]);
    }
    float inv = 1.f / L;
    ushort* yb = ybf + ((size_t)b * HW + q) * 64;
    #pragma unroll
    for (int c = 0; c < CCH; c++) yb[c] = f2bf(acc[c] * inv);
    #pragma unroll
    for (int c = 0; c < CCH; c++) yb[20 + c] = f2bf(fq[((size_t)b * CCH + c) * HW + q]);
    #pragma unroll
    for (int c = 40; c < 64; c++) yb[c] = 0;
}

// ================= weight prep =================
__global__ void prep_w0(const float* __restrict__ cw, const float* __restrict__ rw,
                        ushort* __restrict__ wt0) {
    int idx = blockIdx.x * 256 + threadIdx.x;
    if (idx >= 2 * 9 * 256 * 64) return;
    int ic = idx & 63;
    int oc = (idx >> 6) & 255;
    int t = idx >> 14;
    int kyx = t % 9;
    int br = t / 9;
    float v = 0.f;
    if (ic < 40) {
        const float* w = br ? rw : cw;
        v = w[((size_t)oc * 40 + ic) * 9 + kyx];
    }
    wt0[idx] = f2bf(v);
}

__global__ void prep_wk(const float* __restrict__ cw, const float* __restrict__ rw,
                        ushort* __restrict__ wt) {
    int idx = blockIdx.x * 256 + threadIdx.x;
    if (idx >= 6 * 2 * 9 * 256 * 256) return;
    int ic = idx & 255;
    int oc = (idx >> 8) & 255;
    int t = idx >> 16;
    int kyx = t % 9;
    t /= 9;
    int br = t & 1;
    int s = t >> 1;
    const float* w = br ? rw : cw;
    float v = w[(((size_t)s * 256 + oc) * 256 + ic) * 9 + kyx];
    wt[idx] = f2bf(v);
}

// ================= implicit-im2col GEMM conv, 64oc x 128pos block =================
// 4 waves (2M x 2N); wave tile 32oc x 64pos: per ks 6 ds_read_b128 -> 8 MFMAs
// (0.75 KB LDS read/MFMA vs 1.0 before). Depth-1 named-reg prefetch, single
// barrier per iter, XOR-swizzled LDS. grid x = nt*4 + ot (nt 0..4, ot 0..3), y = bb.
__global__ __launch_bounds__(256) void conv_gemm(
    const ushort* __restrict__ xin, int cin, int cshift, int in_shared, int relu_out,
    const ushort* __restrict__ wt, const float* __restrict__ bias_c,
    const float* __restrict__ bias_r, ushort* __restrict__ xout) {
    __shared__ ushort sA[2][64 * 64];
    __shared__ ushort sB[2][128 * 64];
    const int tid = threadIdx.x;
    const int lane = tid & 63;
    const int wave = tid >> 6;
    const int n16 = lane & 15, quad = lane >> 4;
    const int wm = wave & 1, wn = wave >> 1;
    const int ot = blockIdx.x & 3, nt = blockIdx.x >> 2;
    const int bb = blockIdx.y;
    const int oc0 = ot * 64;
    const ushort* wbr = wt + (size_t)(bb < 8 ? 0 : 1) * 9 * 256 * cin;
    const float* bias = (bb < 8) ? bias_c : bias_r;
    const ushort* inb = xin + (size_t)(in_shared ? (bb & 7) : bb) * HW * cin;

    // A staging: row = tid>>2 (64 rows), chunks sc, sc+4
    const int srowA = tid >> 2;
    const int scA = tid & 3;
    const ushort* aBase = wbr + (size_t)(oc0 + srowA) * cin + scA * 8;
    const int swzA0 = srowA * 64 + ((scA ^ (srowA & 7)) * 8);
    const int swzA1 = srowA * 64 + (((scA + 4) ^ (srowA & 7)) * 8);

    // B staging: row = tid>>1 (128 rows), chunks scB0..scB0+3 (64B contiguous)
    const int srowB = tid >> 1;
    const int scB0 = (tid & 1) * 4;
    const int p = nt * 128 + srowB;
    const bool pok = (p < HW);
    const int pr = pok ? (p / 25) : 0;
    const int pc = pok ? (p % 25) : 0;
    const ushort* bBase = inb + (size_t)(pr * 25 + pc) * cin + scB0 * 8;
    const int swzB0 = srowB * 64 + (((scB0 + 0) ^ (srowB & 7)) * 8);
    const int swzB1 = srowB * 64 + (((scB0 + 1) ^ (srowB & 7)) * 8);
    const int swzB2 = srowB * 64 + (((scB0 + 2) ^ (srowB & 7)) * 8);
    const int swzB3 = srowB * 64 + (((scB0 + 3) ^ (srowB & 7)) * 8);

    const int NIT = 9 << cshift;
    const int cmask = (1 << cshift) - 1;

    uint4 ra0, ra1, rb0, rb1, rb2, rb3;
    auto load_it = [&](int it) {
        int kyx = it >> cshift;
        int ccc = it & cmask;
        int ky = (kyx >= 6) ? 2 : (kyx >= 3 ? 1 : 0);
        int kx = kyx - ky * 3;
        const ushort* aP = aBase + (size_t)(kyx * 256) * cin + ccc * 64;
        ra0 = *(const uint4*)(aP);
        ra1 = *(const uint4*)(aP + 32);
        int rr = pr + ky - 1, cc2 = pc + kx - 1;
        bool v = pok && ((unsigned)rr < 25u) && ((unsigned)cc2 < 25u);
        const ushort* bP = bBase + (ptrdiff_t)(((ky - 1) * 25 + (kx - 1)) * cin + ccc * 64);
        rb0 = v ? *(const uint4*)(bP) : make_uint4(0, 0, 0, 0);
        rb1 = v ? *(const uint4*)(bP + 8) : make_uint4(0, 0, 0, 0);
        rb2 = v ? *(const uint4*)(bP + 16) : make_uint4(0, 0, 0, 0);
        rb3 = v ? *(const uint4*)(bP + 24) : make_uint4(0, 0, 0, 0);
    };
    auto stage = [&](int bufi) {
        *(uint4*)&sA[bufi][swzA0] = ra0; *(uint4*)&sA[bufi][swzA1] = ra1;
        *(uint4*)&sB[bufi][swzB0] = rb0; *(uint4*)&sB[bufi][swzB1] = rb1;
        *(uint4*)&sB[bufi][swzB2] = rb2; *(uint4*)&sB[bufi][swzB3] = rb3;
    };

    f32x4 acc[2][4];
    #pragma unroll
    for (int mf = 0; mf < 2; mf++)
        #pragma unroll
        for (int nf = 0; nf < 4; nf++) acc[mf][nf] = (f32x4)0.f;

    load_it(0);
    stage(0);
    __syncthreads();

    const int arow0 = (wm * 32 + n16) * 64;
    const int brow0 = (wn * 64 + n16) * 64;
    const int h8 = n16 & 7;
    int buf = 0;

    for (int it = 0; it < NIT; ++it) {
        if (it + 1 < NIT) load_it(it + 1);
        #pragma unroll
        for (int ks = 0; ks < 2; ks++) {
            const int swz = ((ks * 4 + quad) ^ h8) * 8;
            bf16x8 a0 = *(const bf16x8*)&sA[buf][arow0 + swz];
            bf16x8 a1 = *(const bf16x8*)&sA[buf][arow0 + 16 * 64 + swz];
            bf16x8 b0 = *(const bf16x8*)&sB[buf][brow0 + swz];
            bf16x8 b1 = *(const bf16x8*)&sB[buf][brow0 + 16 * 64 + swz];
            bf16x8 b2 = *(const bf16x8*)&sB[buf][brow0 + 32 * 64 + swz];
            bf16x8 b3 = *(const bf16x8*)&sB[buf][brow0 + 48 * 64 + swz];
            acc[0][0] = __builtin_amdgcn_mfma_f32_16x16x32_bf16(a0, b0, acc[0][0], 0, 0, 0);
            acc[0][1] = __builtin_amdgcn_mfma_f32_16x16x32_bf16(a0, b1, acc[0][1], 0, 0, 0);
            acc[0][2] = __builtin_amdgcn_mfma_f32_16x16x32_bf16(a0, b2, acc[0][2], 0, 0, 0);
            acc[0][3] = __builtin_amdgcn_mfma_f32_16x16x32_bf16(a0, b3, acc[0][3], 0, 0, 0);
            acc[1][0] = __builtin_amdgcn_mfma_f32_16x16x32_bf16(a1, b0, acc[1][0], 0, 0, 0);
            acc[1][1] = __builtin_amdgcn_mfma_f32_16x16x32_bf16(a1, b1, acc[1][1], 0, 0, 0);
            acc[1][2] = __builtin_amdgcn_mfma_f32_16x16x32_bf16(a1, b2, acc[1][2], 0, 0, 0);
            acc[1][3] = __builtin_amdgcn_mfma_f32_16x16x32_bf16(a1, b3, acc[1][3], 0, 0, 0);
        }
        if (it + 1 < NIT) {
            // writes to buf^1 protected by previous iteration's barrier
            stage(buf ^ 1);
            __syncthreads();
            buf ^= 1;
        }
    }

    #pragma unroll
    for (int mf = 0; mf < 2; mf++) {
        int ocb = oc0 + wm * 32 + mf * 16 + quad * 4;
        float4 bv = *(const float4*)(bias + ocb);
        #pragma unroll
        for (int nf = 0; nf < 4; nf++) {
            int pcol = nt * 128 + wn * 64 + nf * 16 + n16;
            if (pcol >= HW) continue;
            f32x4 a = acc[mf][nf];
            float v0 = a[0] + bv.x;
            float v1 = a[1] + bv.y;
            float v2 = a[2] + bv.z;
            float v3 = a[3] + bv.w;
            if (relu_out) {
                v0 = fmaxf(v0, 0.f); v1 = fmaxf(v1, 0.f);
                v2 = fmaxf(v2, 0.f); v3 = fmaxf(v3, 0.f);
            }
            uint2 st;
            st.x = (unsigned)f2bf(v0) | ((unsigned)f2bf(v1) << 16);
            st.y = (unsigned)f2bf(v2) | ((unsigned)f2bf(v3) << 16);
            *(uint2*)(&xout[((size_t)bb * HW + pcol) * 256 + ocb]) = st;
        }
    }
}

// ================= heads =================
__global__ __launch_bounds__(256) void heads(const ushort* __restrict__ X,
                                             const float* __restrict__ wcls, const float* __restrict__ bcls,
                                             const float* __restrict__ gcls, const float* __restrict__ becls,
                                             const float* __restrict__ wctr, const float* __restrict__ bctr,
                                             const float* __restrict__ gctr, const float* __restrict__ bectr,
                                             const float* __restrict__ woff, const float* __restrict__ boff,
                                             const float* __restrict__ goff, const float* __restrict__ beoff,
                                             const float* __restrict__ si, const float* __restrict__ bi,
                                             float* __restrict__ out) {
    int g = blockIdx.x * 256 + threadIdx.x;
    if (g >= BATCH * HW) return;
    int b = g / HW, p = g % HW;
    const ushort* fc = X + ((size_t)b * HW + p) * 256;
    const ushort* fr = X + ((size_t)(8 + b) * HW + p) * 256;
    float ac = 0.f, at = 0.f, a0 = 0.f, a1 = 0.f, a2 = 0.f, a3 = 0.f;
    for (int c0 = 0; c0 < 256; c0 += 8) {
        uint4 vc = *(const uint4*)(fc + c0);
        uint4 vr = *(const uint4*)(fr + c0);
        unsigned wc_[4] = {vc.x, vc.y, vc.z, vc.w};
        unsigned wr_[4] = {vr.x, vr.y, vr.z, vr.w};
        #pragma unroll
        for (int j = 0; j < 4; j++) {
            float cl = __uint_as_float(wc_[j] << 16);
            float ch = __uint_as_float(wc_[j] & 0xFFFF0000u);
            float rl = __uint_as_float(wr_[j] << 16);
            float rh = __uint_as_float(wr_[j] & 0xFFFF0000u);
            int c = c0 + j * 2;
            ac += wcls[c] * cl + wcls[c + 1] * ch;
            at += wctr[c] * cl + wctr[c + 1] * ch;
            a0 += woff[c] * rl + woff[c + 1] * rh;
            a1 += woff[256 + c] * rl + woff[256 + c + 1] * rh;
            a2 += woff[512 + c] * rl + woff[512 + c + 1] * rh;
            a3 += woff[768 + c] * rl + woff[768 + c + 1] * rh;
        }
    }
    const float bns = 1.f / sqrtf(1.f + 1e-5f);
    float cls = (ac + bcls[0]) * (gcls[0] * bns) + becls[0];
    float ctr = (at + bctr[0]) * (gctr[0] * bns) + bectr[0];
    float sv = si[0], bv = bi[0];
    float o0 = (a0 + boff[0]) * (goff[0] * bns) + beoff[0];
    float o1 = (a1 + boff[1]) * (goff[1] * bns) + beoff[1];
    float o2 = (a2 + boff[2]) * (goff[2] * bns) + beoff[2];
    float o3 = (a3 + boff[3]) * (goff[3] * bns) + beoff[3];
    float e0 = __expf(sv * o0 + bv) * 8.f;
    float e1 = __expf(sv * o1 + bv) * 8.f;
    float e2 = __expf(sv * o2 + bv) * 8.f;
    float e3 = __expf(sv * o3 + bv) * 8.f;
    float gx = 3.f + 8.f * (float)(p % SSIDE);
    float gy = 3.f + 8.f * (float)(p / SSIDE);
    out[g] = cls;
    out[BATCH * HW + g] = ctr;
    float* bbx = out + 2 * BATCH * HW + (size_t)g * 4;
    bbx[0] = gx - e0;
    bbx[1] = gy - e1;
    bbx[2] = gx + e2;
    bbx[3] = gy + e3;
}

extern "C" void kernel_launch(void* const* d_in, const int* in_sizes, int n_in,
                              void* d_out, int out_size, void* d_ws, size_t ws_size,
                              hipStream_t stream) {
    const float* fm     = (const float*)d_in[0];
    const float* fq     = (const float*)d_in[1];
    const float* cls1_w = (const float*)d_in[2];
    const float* cls1_b = (const float*)d_in[3];
    const float* clsk_w = (const float*)d_in[4];
    const float* clsk_b = (const float*)d_in[5];
    const float* reg1_w = (const float*)d_in[6];
    const float* reg1_b = (const float*)d_in[7];
    const float* regk_w = (const float*)d_in[8];
    const float* regk_b = (const float*)d_in[9];
    const float* w_cls  = (const float*)d_in[10];
    const float* b_cls  = (const float*)d_in[11];
    const float* g_cls  = (const float*)d_in[12];
    const float* be_cls = (const float*)d_in[13];
    const float* w_ctr  = (const float*)d_in[14];
    const float* b_ctr  = (const float*)d_in[15];
    const float* g_ctr  = (const float*)d_in[16];
    const float* be_ctr = (const float*)d_in[17];
    const float* w_off  = (const float*)d_in[18];
    const float* b_off  = (const float*)d_in[19];
    const float* g_off  = (const float*)d_in[20];
    const float* be_off = (const float*)d_in[21];
    const float* si     = (const float*)d_in[22];
    const float* bi     = (const float*)d_in[23];

    char* ws = (char*)d_ws;
    ushort* YBF  = (ushort*)(ws + YBF_OFF);
    ushort* XA   = (ushort*)(ws + XA_OFF);
    ushort* XB   = (ushort*)(ws + XB_OFF);
    ushort* WT0  = (ushort*)(ws + WT0_OFF);
    ushort* WT   = (ushort*)(ws + WT_OFF);
    ushort* FMT  = (ushort*)(ws + FMT_OFF);
    ushort* FM32 = (ushort*)(ws + FM32_OFF);
    ushort* FQB  = (ushort*)(ws + FQB_OFF);
    char*   PART = ws + PART_OFF;

    // --- attention (scratch aliases XB/WT region; consumed before those are written) ---
    prep_fm<<<dim3(59, 8), 256, 0, stream>>>(fm, FMT, FM32);
    prep_fmz<<<dim3(708), 256, 0, stream>>>(FM32);
    prep_fq<<<dim3(20), 256, 0, stream>>>(fq, FQB);
    attn_flash<<<dim3(3, NKC, 8), 512, 0, stream>>>(FMT, FM32, FQB, PART);
    attn_merge<<<dim3(20), 256, 0, stream>>>(PART, fq, YBF);

    // --- weight transposes (overwrite attention scratch) ---
    prep_w0<<<dim3((2 * 9 * 256 * 64 + 255) / 256), 256, 0, stream>>>(cls1_w, reg1_w, WT0);
    prep_wk<<<dim3((6 * 2 * 9 * 256 * 256 + 255) / 256), 256, 0, stream>>>(clsk_w, regk_w, WT);

    // --- conv tower: grid x = nt*4 + ot (20), y = bb (16) ---
    conv_gemm<<<dim3(20, 16), 256, 0, stream>>>(YBF, 64, 0, 1, 1, WT0, cls1_b, reg1_b, XA);

    ushort* cur = XA;
    ushort* nxt = XB;
    for (int s = 0; s < 6; s++) {
        int relu_out = (s < 5) ? 1 : 0;
        conv_gemm<<<dim3(20, 16), 256, 0, stream>>>(cur, 256, 2, 0, relu_out,
            WT + (size_t)s * 2 * 9 * 256 * 256,
            clsk_b + (size_t)s * 256, regk_b + (size_t)s * 256, nxt);
        ushort* tmp = cur; cur = nxt; nxt = tmp;
    }

    heads<<<dim3(20), 256, 0, stream>>>(cur, w_cls, b_cls, g_cls, be_cls,
                                        w_ctr, b_ctr, g_ctr, be_ctr,
                                        w_off, b_off, g_off, be_off, si, bi,
                                        (float*)d_out);
}

// Round 14
// 405.503 us; speedup vs baseline: 1.0728x; 1.0728x over previous
//
#include <hip/hip_runtime.h>
#include <math.h>

#define BATCH 8
#define CCH 20
#define THW 15000
#define HW 625
#define SSIDE 25

#define NKEY 15000
#define TPAD 15104      // 59*256, padded key dim
#define NKT 118         // ceil(15000/128) k-tiles of 128
#define NKC 15          // k-chunks (8 tiles each, last gets 6)

typedef __attribute__((ext_vector_type(8))) short bf16x8;
typedef __attribute__((ext_vector_type(4))) float f32x4;

// ---- ws layout (byte offsets) ----
#define YBF_OFF  0ULL
#define XA_OFF   640000ULL
#define XB_OFF   5760000ULL
#define WT0_OFF  10880000ULL
#define WT_OFF   11469824ULL
#define FMT_OFF  5760000ULL
#define FM32_OFF 13493248ULL
#define FQB_OFF  21226496ULL
#define PART_OFF XA_OFF   // bf16 partials: 8*5*15*128*48 B = 3.69 MB < 5.12 MB

__device__ __forceinline__ ushort f2bf(float x) {
    unsigned u = __float_as_uint(x);
    u = (u + 0x7FFFu + ((u >> 16) & 1u)) >> 16;
    return (ushort)u;
}
__device__ __forceinline__ float bf2f(ushort v) {
    return __uint_as_float(((unsigned)v) << 16);
}

// ===== prep: fm -> fmbT (t-major rows of 32 ch) + fmb32 (ch-major), bf16 =====
__global__ __launch_bounds__(256) void prep_fm(const float* __restrict__ fm,
                                               ushort* __restrict__ fmbT,
                                               ushort* __restrict__ fmb32) {
    __shared__ ushort sT2[256][34];
    const int tid = threadIdx.x;
    const int t0 = blockIdx.x * 256;
    const int b = blockIdx.y;
    const int t = t0 + tid;
    #pragma unroll 4
    for (int c = 0; c < CCH; c++) {
        float v = (t < NKEY) ? fm[((size_t)b * CCH + c) * THW + t] : 0.f;
        ushort h = f2bf(v);
        sT2[tid][c] = h;
        fmb32[((size_t)b * 32 + c) * TPAD + t] = h;
    }
    __syncthreads();
    const int g = tid >> 4, j = tid & 15;
    uint* dstb = (uint*)fmbT + ((size_t)b * TPAD + t0) * 16 + j;
    #pragma unroll
    for (int i = 0; i < 16; i++) {
        int r = g + 16 * i;
        uint v = 0;
        if (j < 10) v = *(const uint*)&sT2[r][2 * j];
        dstb[(size_t)r * 16] = v;
    }
}

// zero fmb32 channel rows 20..31
__global__ __launch_bounds__(256) void prep_fmz(ushort* __restrict__ fmb32) {
    int idx = blockIdx.x * 256 + threadIdx.x;
    if (idx >= 181248) return;             // 8*12*1888
    int t8 = idx % 1888;
    int rest = idx / 1888;
    int cz = rest % 12, b = rest / 12;
    uint4 z = make_uint4(0, 0, 0, 0);
    *(uint4*)(fmb32 + ((size_t)(b * 32 + 20 + cz)) * TPAD + t8 * 8) = z;
}

// fq -> fqb bf16 [b][640][32], scale 1/sqrt(512)*log2(e) folded
__global__ __launch_bounds__(256) void prep_fq(const float* __restrict__ fq,
                                               ushort* __restrict__ fqb) {
    int idx = blockIdx.x * 256 + threadIdx.x;
    if (idx >= BATCH * 640) return;
    int b = idx / 640, q = idx % 640;
    const float qscale = 1.4426950408889634f * 0.04419417382415922f;
    ushort* dst = fqb + (size_t)idx * 32;
    #pragma unroll 4
    for (int c = 0; c < CCH; c++) {
        float v = (q < HW) ? fq[((size_t)b * CCH + c) * HW + q] * qscale : 0.f;
        dst[c] = f2bf(v);
    }
    #pragma unroll
    for (int c = CCH; c < 32; c++) dst[c] = 0;
}

// ===== MFMA flash attention, 512-thread blocks (R12 version, unchanged) =====
__global__ __launch_bounds__(512) void attn_flash(const ushort* __restrict__ fmbT,
                                                  const ushort* __restrict__ fmb32,
                                                  const ushort* __restrict__ fqb,
                                                  char* __restrict__ part) {
    __shared__ __align__(16) ushort sP[8][2][16][136];
    const int tid = threadIdx.x;
    const int wave = tid >> 6, lane = tid & 63;
    const int q16 = lane & 15, quad = lane >> 4;
    const int qt = blockIdx.x * 2 + (wave >> 2);
    const int wq = wave & 3;
    const int kc = blockIdx.y, b = blockIdx.z;
    if (qt >= 5) return;

    bf16x8 Qf[2];
    #pragma unroll
    for (int nf = 0; nf < 2; nf++)
        Qf[nf] = *(const bf16x8*)(fqb + ((size_t)(b * 640 + qt * 128 + wq * 32 + nf * 16 + q16) << 5) + quad * 8);

    f32x4 O[2][2];
    #pragma unroll
    for (int nf = 0; nf < 2; nf++) { O[nf][0] = (f32x4)0.f; O[nf][1] = (f32x4)0.f; }
    float lp0 = 0.f, lp1 = 0.f;
    const f32x4 zz = (f32x4)0.f;

    const int kt0 = kc * 8;
    const int kt1 = (kt0 + 8 < NKT) ? kt0 + 8 : NKT;

    for (int kt = kt0; kt < kt1; kt++) {
        const int t0 = kt << 7;
        const bool tail = (t0 + 128 > NKEY);
        bf16x8 Ak[8], Av[8];
        #pragma unroll
        for (int m = 0; m < 8; m++)
            Ak[m] = *(const bf16x8*)(fmbT + ((size_t)(b * TPAD + t0 + m * 16 + q16) << 5) + quad * 8);
        #pragma unroll
        for (int mp = 0; mp < 4; mp++)
            #pragma unroll
            for (int cf = 0; cf < 2; cf++)
                Av[mp * 2 + cf] = *(const bf16x8*)(fmb32 + (size_t)(b * 32 + cf * 16 + q16) * TPAD + t0 + mp * 32 + quad * 8);

        f32x4 S[8][2];
        #pragma unroll
        for (int m = 0; m < 8; m++) {
            S[m][0] = __builtin_amdgcn_mfma_f32_16x16x32_bf16(Ak[m], Qf[0], zz, 0, 0, 0);
            S[m][1] = __builtin_amdgcn_mfma_f32_16x16x32_bf16(Ak[m], Qf[1], zz, 0, 0, 0);
        }

        #pragma unroll
        for (int nf = 0; nf < 2; nf++) {
            float lacc = 0.f;
            #pragma unroll
            for (int m = 0; m < 8; m++) {
                float p[4];
                #pragma unroll
                for (int i = 0; i < 4; i++) {
                    float v = __builtin_amdgcn_exp2f(S[m][nf][i]);
                    if (tail && (t0 + m * 16 + quad * 4 + i >= NKEY)) v = 0.f;
                    p[i] = v;
                }
                lacc += (p[0] + p[1]) + (p[2] + p[3]);
                uint pk0 = __builtin_amdgcn_perm(__float_as_uint(p[1]) + 0x8000u,
                                                 __float_as_uint(p[0]) + 0x8000u, 0x07060302u);
                uint pk1 = __builtin_amdgcn_perm(__float_as_uint(p[3]) + 0x8000u,
                                                 __float_as_uint(p[2]) + 0x8000u, 0x07060302u);
                uint* dst = (uint*)&sP[wave][nf][q16][m * 16 + quad * 4];
                dst[0] = pk0;
                dst[1] = pk1;
            }
            if (nf == 0) lp0 += lacc; else lp1 += lacc;
        }

        #pragma unroll
        for (int mp = 0; mp < 4; mp++) {
            bf16x8 Bp0 = *(const bf16x8*)&sP[wave][0][q16][mp * 32 + quad * 8];
            bf16x8 Bp1 = *(const bf16x8*)&sP[wave][1][q16][mp * 32 + quad * 8];
            O[0][0] = __builtin_amdgcn_mfma_f32_16x16x32_bf16(Av[mp * 2 + 0], Bp0, O[0][0], 0, 0, 0);
            O[0][1] = __builtin_amdgcn_mfma_f32_16x16x32_bf16(Av[mp * 2 + 1], Bp0, O[0][1], 0, 0, 0);
            O[1][0] = __builtin_amdgcn_mfma_f32_16x16x32_bf16(Av[mp * 2 + 0], Bp1, O[1][0], 0, 0, 0);
            O[1][1] = __builtin_amdgcn_mfma_f32_16x16x32_bf16(Av[mp * 2 + 1], Bp1, O[1][1], 0, 0, 0);
        }
    }

    lp0 += __shfl_xor(lp0, 16); lp0 += __shfl_xor(lp0, 32);
    lp1 += __shfl_xor(lp1, 16); lp1 += __shfl_xor(lp1, 32);

    #pragma unroll
    for (int nf = 0; nf < 2; nf++) {
        int ql = wq * 32 + nf * 16 + q16;
        size_t rec = ((((size_t)b * 5 + qt) * NKC + kc) * 128 + ql) * 48;
        uint2 pk;
        pk.x = (unsigned)f2bf(O[nf][0][0]) | ((unsigned)f2bf(O[nf][0][1]) << 16);
        pk.y = (unsigned)f2bf(O[nf][0][2]) | ((unsigned)f2bf(O[nf][0][3]) << 16);
        *(uint2*)(part + rec + quad * 8) = pk;
        if (quad == 0) {
            uint2 pk1;
            pk1.x = (unsigned)f2bf(O[nf][1][0]) | ((unsigned)f2bf(O[nf][1][1]) << 16);
            pk1.y = (unsigned)f2bf(O[nf][1][2]) | ((unsigned)f2bf(O[nf][1][3]) << 16);
            *(uint2*)(part + rec + 32) = pk1;
            *(float*)(part + rec + 40) = (nf == 0) ? lp0 : lp1;
        }
    }
}

// merge partials -> YBF bf16 NHWC [b][625][64]
__global__ __launch_bounds__(256) void attn_merge(const char* __restrict__ part,
                                                  const float* __restrict__ fq,
                                                  ushort* __restrict__ ybf) {
    int g = blockIdx.x * 256 + threadIdx.x;
    if (g >= BATCH * HW) return;
    int b = g / HW, q = g % HW;
    int qt = q >> 7, ql = q & 127;
    const char* pb = part + ((((size_t)b * 5 + qt) * NKC) * 128 + ql) * 48;
    float L = 0.f;
    float acc[CCH];
    #pragma unroll
    for (int c = 0; c < CCH; c++) acc[c] = 0.f;
    for (int kc = 0; kc < NKC; kc++) {
        const char* rec = pb + (size_t)kc * 128 * 48;
        L += *(const float*)(rec + 40);
        const ushort* av = (const ushort*)rec;
        #pragma unroll
        for (int c = 0; c < CCH; c++) acc[c] += bf2f(av[c]);
    }
    float inv = 1.f / L;
    ushort* yb = ybf + ((size_t)b * HW + q) * 64;
    #pragma unroll
    for (int c = 0; c < CCH; c++) yb[c] = f2bf(acc[c] * inv);
    #pragma unroll
    for (int c = 0; c < CCH; c++) yb[20 + c] = f2bf(fq[((size_t)b * CCH + c) * HW + q]);
    #pragma unroll
    for (int c = 40; c < 64; c++) yb[c] = 0;
}

// ================= weight prep =================
__global__ void prep_w0(const float* __restrict__ cw, const float* __restrict__ rw,
                        ushort* __restrict__ wt0) {
    int idx = blockIdx.x * 256 + threadIdx.x;
    if (idx >= 2 * 9 * 256 * 64) return;
    int ic = idx & 63;
    int oc = (idx >> 6) & 255;
    int t = idx >> 14;
    int kyx = t % 9;
    int br = t / 9;
    float v = 0.f;
    if (ic < 40) {
        const float* w = br ? rw : cw;
        v = w[((size_t)oc * 40 + ic) * 9 + kyx];
    }
    wt0[idx] = f2bf(v);
}

__global__ void prep_wk(const float* __restrict__ cw, const float* __restrict__ rw,
                        ushort* __restrict__ wt) {
    int idx = blockIdx.x * 256 + threadIdx.x;
    if (idx >= 6 * 2 * 9 * 256 * 256) return;
    int ic = idx & 255;
    int oc = (idx >> 8) & 255;
    int t = idx >> 16;
    int kyx = t % 9;
    t /= 9;
    int br = t & 1;
    int s = t >> 1;
    const float* w = br ? rw : cw;
    float v = w[(((size_t)s * 256 + oc) * 256 + ic) * 9 + kyx];
    wt[idx] = f2bf(v);
}

// ================= implicit-im2col GEMM conv, 64x64 tile, depth-2 pipeline =================
// Dynamic loop unrolled by 2 with TWO NAMED register sets (A = even iters, B = odd):
// load for iter k+2 issues at top of iter k -> ~2 iteration bodies of latency cover.
// Static indices only (no scratch spill). Single barrier per iteration.
// XOR-swizzled LDS -> conflict-free ds_read_b128. grid x = nt*4+ot (40), y = bb (16).
__global__ __launch_bounds__(256) void conv_gemm(
    const ushort* __restrict__ xin, int cin, int cshift, int in_shared, int relu_out,
    const ushort* __restrict__ wt, const float* __restrict__ bias_c,
    const float* __restrict__ bias_r, ushort* __restrict__ xout) {
    __shared__ ushort sA[2][64 * 64];
    __shared__ ushort sB[2][64 * 64];
    const int tid = threadIdx.x;
    const int lane = tid & 63;
    const int wave = tid >> 6;
    const int n16 = lane & 15, quad = lane >> 4;
    const int wm = wave & 1, wn = wave >> 1;
    const int ot = blockIdx.x & 3, nt = blockIdx.x >> 2;
    const int bb = blockIdx.y;
    const int oc0 = ot * 64;
    const ushort* wbr = wt + (size_t)(bb < 8 ? 0 : 1) * 9 * 256 * cin;
    const float* bias = (bb < 8) ? bias_c : bias_r;
    const ushort* inb = xin + (size_t)(in_shared ? (bb & 7) : bb) * HW * cin;

    const int srow = tid >> 2;
    const int sc = tid & 3;
    const ushort* aBase = wbr + (size_t)(oc0 + srow) * cin + sc * 8;
    const int p = nt * 64 + srow;
    const bool pok = (p < HW);
    const int pr = pok ? (p / 25) : 0;
    const int pc = pok ? (p % 25) : 0;
    const ushort* bBase = inb + (size_t)(pr * 25 + pc) * cin + sc * 8;
    const int swz0 = srow * 64 + ((sc ^ (srow & 7)) * 8);
    const int swz1 = srow * 64 + (((sc + 4) ^ (srow & 7)) * 8);

    const int NIT = 9 << cshift;
    const int cmask = (1 << cshift) - 1;

    // named register set A (even iterations) and B (odd iterations)
    uint4 raA0, raA1, rbA0, rbA1;
    uint4 raB0, raB1, rbB0, rbB1;
    auto loadA = [&](int it) {
        int kyx = it >> cshift;
        int ccc = it & cmask;
        int ky = (kyx >= 6) ? 2 : (kyx >= 3 ? 1 : 0);
        int kx = kyx - ky * 3;
        const ushort* aP = aBase + (size_t)(kyx * 256) * cin + ccc * 64;
        raA0 = *(const uint4*)(aP);
        raA1 = *(const uint4*)(aP + 32);
        int rr = pr + ky - 1, cc2 = pc + kx - 1;
        bool v = pok && ((unsigned)rr < 25u) && ((unsigned)cc2 < 25u);
        const ushort* bP = bBase + (ptrdiff_t)(((ky - 1) * 25 + (kx - 1)) * cin + ccc * 64);
        rbA0 = v ? *(const uint4*)(bP) : make_uint4(0, 0, 0, 0);
        rbA1 = v ? *(const uint4*)(bP + 32) : make_uint4(0, 0, 0, 0);
    };
    auto loadB = [&](int it) {
        int kyx = it >> cshift;
        int ccc = it & cmask;
        int ky = (kyx >= 6) ? 2 : (kyx >= 3 ? 1 : 0);
        int kx = kyx - ky * 3;
        const ushort* aP = aBase + (size_t)(kyx * 256) * cin + ccc * 64;
        raB0 = *(const uint4*)(aP);
        raB1 = *(const uint4*)(aP + 32);
        int rr = pr + ky - 1, cc2 = pc + kx - 1;
        bool v = pok && ((unsigned)rr < 25u) && ((unsigned)cc2 < 25u);
        const ushort* bP = bBase + (ptrdiff_t)(((ky - 1) * 25 + (kx - 1)) * cin + ccc * 64);
        rbB0 = v ? *(const uint4*)(bP) : make_uint4(0, 0, 0, 0);
        rbB1 = v ? *(const uint4*)(bP + 32) : make_uint4(0, 0, 0, 0);
    };
    auto stageA = [&](int bufi) {
        *(uint4*)&sA[bufi][swz0] = raA0; *(uint4*)&sA[bufi][swz1] = raA1;
        *(uint4*)&sB[bufi][swz0] = rbA0; *(uint4*)&sB[bufi][swz1] = rbA1;
    };
    auto stageB = [&](int bufi) {
        *(uint4*)&sA[bufi][swz0] = raB0; *(uint4*)&sA[bufi][swz1] = raB1;
        *(uint4*)&sB[bufi][swz0] = rbB0; *(uint4*)&sB[bufi][swz1] = rbB1;
    };

    f32x4 acc00 = (f32x4)0.f, acc01 = (f32x4)0.f;
    f32x4 acc10 = (f32x4)0.f, acc11 = (f32x4)0.f;

    const int arow0 = wm * 32 + n16;
    const int brow0 = wn * 32 + n16;
    const int h8 = n16 & 7;

    auto mfma_tile = [&](int bufi) {
        #pragma unroll
        for (int ks = 0; ks < 2; ks++) {
            const int swz = ((ks * 4 + quad) ^ h8) * 8;
            bf16x8 a0 = *(const bf16x8*)&sA[bufi][arow0 * 64 + swz];
            bf16x8 a1 = *(const bf16x8*)&sA[bufi][(arow0 + 16) * 64 + swz];
            bf16x8 b0 = *(const bf16x8*)&sB[bufi][brow0 * 64 + swz];
            bf16x8 b1 = *(const bf16x8*)&sB[bufi][(brow0 + 16) * 64 + swz];
            acc00 = __builtin_amdgcn_mfma_f32_16x16x32_bf16(a0, b0, acc00, 0, 0, 0);
            acc01 = __builtin_amdgcn_mfma_f32_16x16x32_bf16(a0, b1, acc01, 0, 0, 0);
            acc10 = __builtin_amdgcn_mfma_f32_16x16x32_bf16(a1, b0, acc10, 0, 0, 0);
            acc11 = __builtin_amdgcn_mfma_f32_16x16x32_bf16(a1, b1, acc11, 0, 0, 0);
        }
    };

    // prologue: iter 0 -> set A (staged), iter 1 -> set B (in regs)
    loadA(0);
    stageA(0);
    if (NIT > 1) loadB(1);
    __syncthreads();

    int buf = 0;
    for (int it = 0; it + 1 < NIT; it += 2) {
        // even iteration `it` (data in buf; set A free after prologue/stage)
        if (it + 2 < NIT) loadA(it + 2);
        mfma_tile(buf);
        stageB(buf ^ 1);           // iter it+1 data; writes protected by prev barrier
        __syncthreads();
        buf ^= 1;
        // odd iteration `it+1`
        if (it + 3 < NIT) loadB(it + 3);
        mfma_tile(buf);
        if (it + 2 < NIT) {
            stageA(buf ^ 1);       // iter it+2 data
            __syncthreads();
            buf ^= 1;
        }
    }
    if (NIT & 1) mfma_tile(buf);   // last (even-indexed) iteration, already staged

    f32x4 accs[2][2] = {{acc00, acc01}, {acc10, acc11}};
    #pragma unroll
    for (int mf = 0; mf < 2; mf++) {
        int ocb = oc0 + wm * 32 + mf * 16 + quad * 4;
        float4 bv = *(const float4*)(bias + ocb);
        #pragma unroll
        for (int nf = 0; nf < 2; nf++) {
            int pcol = nt * 64 + wn * 32 + nf * 16 + n16;
            if (pcol >= HW) continue;
            f32x4 a = accs[mf][nf];
            float v0 = a[0] + bv.x;
            float v1 = a[1] + bv.y;
            float v2 = a[2] + bv.z;
            float v3 = a[3] + bv.w;
            if (relu_out) {
                v0 = fmaxf(v0, 0.f); v1 = fmaxf(v1, 0.f);
                v2 = fmaxf(v2, 0.f); v3 = fmaxf(v3, 0.f);
            }
            uint2 st;
            st.x = (unsigned)f2bf(v0) | ((unsigned)f2bf(v1) << 16);
            st.y = (unsigned)f2bf(v2) | ((unsigned)f2bf(v3) << 16);
            *(uint2*)(&xout[((size_t)bb * HW + pcol) * 256 + ocb]) = st;
        }
    }
}

// ================= heads =================
__global__ __launch_bounds__(256) void heads(const ushort* __restrict__ X,
                                             const float* __restrict__ wcls, const float* __restrict__ bcls,
                                             const float* __restrict__ gcls, const float* __restrict__ becls,
                                             const float* __restrict__ wctr, const float* __restrict__ bctr,
                                             const float* __restrict__ gctr, const float* __restrict__ bectr,
                                             const float* __restrict__ woff, const float* __restrict__ boff,
                                             const float* __restrict__ goff, const float* __restrict__ beoff,
                                             const float* __restrict__ si, const float* __restrict__ bi,
                                             float* __restrict__ out) {
    int g = blockIdx.x * 256 + threadIdx.x;
    if (g >= BATCH * HW) return;
    int b = g / HW, p = g % HW;
    const ushort* fc = X + ((size_t)b * HW + p) * 256;
    const ushort* fr = X + ((size_t)(8 + b) * HW + p) * 256;
    float ac = 0.f, at = 0.f, a0 = 0.f, a1 = 0.f, a2 = 0.f, a3 = 0.f;
    for (int c0 = 0; c0 < 256; c0 += 8) {
        uint4 vc = *(const uint4*)(fc + c0);
        uint4 vr = *(const uint4*)(fr + c0);
        unsigned wc_[4] = {vc.x, vc.y, vc.z, vc.w};
        unsigned wr_[4] = {vr.x, vr.y, vr.z, vr.w};
        #pragma unroll
        for (int j = 0; j < 4; j++) {
            float cl = __uint_as_float(wc_[j] << 16);
            float ch = __uint_as_float(wc_[j] & 0xFFFF0000u);
            float rl = __uint_as_float(wr_[j] << 16);
            float rh = __uint_as_float(wr_[j] & 0xFFFF0000u);
            int c = c0 + j * 2;
            ac += wcls[c] * cl + wcls[c + 1] * ch;
            at += wctr[c] * cl + wctr[c + 1] * ch;
            a0 += woff[c] * rl + woff[c + 1] * rh;
            a1 += woff[256 + c] * rl + woff[256 + c + 1] * rh;
            a2 += woff[512 + c] * rl + woff[512 + c + 1] * rh;
            a3 += woff[768 + c] * rl + woff[768 + c + 1] * rh;
        }
    }
    const float bns = 1.f / sqrtf(1.f + 1e-5f);
    float cls = (ac + bcls[0]) * (gcls[0] * bns) + becls[0];
    float ctr = (at + bctr[0]) * (gctr[0] * bns) + bectr[0];
    float sv = si[0], bv = bi[0];
    float o0 = (a0 + boff[0]) * (goff[0] * bns) + beoff[0];
    float o1 = (a1 + boff[1]) * (goff[1] * bns) + beoff[1];
    float o2 = (a2 + boff[2]) * (goff[2] * bns) + beoff[2];
    float o3 = (a3 + boff[3]) * (goff[3] * bns) + beoff[3];
    float e0 = __expf(sv * o0 + bv) * 8.f;
    float e1 = __expf(sv * o1 + bv) * 8.f;
    float e2 = __expf(sv * o2 + bv) * 8.f;
    float e3 = __expf(sv * o3 + bv) * 8.f;
    float gx = 3.f + 8.f * (float)(p % SSIDE);
    float gy = 3.f + 8.f * (float)(p / SSIDE);
    out[g] = cls;
    out[BATCH * HW + g] = ctr;
    float* bbx = out + 2 * BATCH * HW + (size_t)g * 4;
    bbx[0] = gx - e0;
    bbx[1] = gy - e1;
    bbx[2] = gx + e2;
    bbx[3] = gy + e3;
}

extern "C" void kernel_launch(void* const* d_in, const int* in_sizes, int n_in,
                              void* d_out, int out_size, void* d_ws, size_t ws_size,
                              hipStream_t stream) {
    const float* fm     = (const float*)d_in[0];
    const float* fq     = (const float*)d_in[1];
    const float* cls1_w = (const float*)d_in[2];
    const float* cls1_b = (const float*)d_in[3];
    const float* clsk_w = (const float*)d_in[4];
    const float* clsk_b = (const float*)d_in[5];
    const float* reg1_w = (const float*)d_in[6];
    const float* reg1_b = (const float*)d_in[7];
    const float* regk_w = (const float*)d_in[8];
    const float* regk_b = (const float*)d_in[9];
    const float* w_cls  = (const float*)d_in[10];
    const float* b_cls  = (const float*)d_in[11];
    const float* g_cls  = (const float*)d_in[12];
    const float* be_cls = (const float*)d_in[13];
    const float* w_ctr  = (const float*)d_in[14];
    const float* b_ctr  = (const float*)d_in[15];
    const float* g_ctr  = (const float*)d_in[16];
    const float* be_ctr = (const float*)d_in[17];
    const float* w_off  = (const float*)d_in[18];
    const float* b_off  = (const float*)d_in[19];
    const float* g_off  = (const float*)d_in[20];
    const float* be_off = (const float*)d_in[21];
    const float* si     = (const float*)d_in[22];
    const float* bi     = (const float*)d_in[23];

    char* ws = (char*)d_ws;
    ushort* YBF  = (ushort*)(ws + YBF_OFF);
    ushort* XA   = (ushort*)(ws + XA_OFF);
    ushort* XB   = (ushort*)(ws + XB_OFF);
    ushort* WT0  = (ushort*)(ws + WT0_OFF);
    ushort* WT   = (ushort*)(ws + WT_OFF);
    ushort* FMT  = (ushort*)(ws + FMT_OFF);
    ushort* FM32 = (ushort*)(ws + FM32_OFF);
    ushort* FQB  = (ushort*)(ws + FQB_OFF);
    char*   PART = ws + PART_OFF;

    // --- attention (scratch aliases XB/WT region; consumed before those are written) ---
    prep_fm<<<dim3(59, 8), 256, 0, stream>>>(fm, FMT, FM32);
    prep_fmz<<<dim3(708), 256, 0, stream>>>(FM32);
    prep_fq<<<dim3(20), 256, 0, stream>>>(fq, FQB);
    attn_flash<<<dim3(3, NKC, 8), 512, 0, stream>>>(FMT, FM32, FQB, PART);
    attn_merge<<<dim3(20), 256, 0, stream>>>(PART, fq, YBF);

    // --- weight transposes (overwrite attention scratch) ---
    prep_w0<<<dim3((2 * 9 * 256 * 64 + 255) / 256), 256, 0, stream>>>(cls1_w, reg1_w, WT0);
    prep_wk<<<dim3((6 * 2 * 9 * 256 * 256 + 255) / 256), 256, 0, stream>>>(clsk_w, regk_w, WT);

    // --- conv tower: grid x = nt*4 + ot (40), y = bb (16) ---
    conv_gemm<<<dim3(40, 16), 256, 0, stream>>>(YBF, 64, 0, 1, 1, WT0, cls1_b, reg1_b, XA);

    ushort* cur = XA;
    ushort* nxt = XB;
    for (int s = 0; s < 6; s++) {
        int relu_out = (s < 5) ? 1 : 0;
        conv_gemm<<<dim3(40, 16), 256, 0, stream>>>(cur, 256, 2, 0, relu_out,
            WT + (size_t)s * 2 * 9 * 256 * 256,
            clsk_b + (size_t)s * 256, regk_b + (size_t)s * 256, nxt);
        ushort* tmp = cur; cur = nxt; nxt = tmp;
    }

    heads<<<dim3(20), 256, 0, stream>>>(cur, w_cls, b_cls, g_cls, be_cls,
                                        w_ctr, b_ctr, g_ctr, be_ctr,
                                        w_off, b_off, g_off, be_off, si, bi,
                                        (float*)d_out);
}

// Round 15
// 404.438 us; speedup vs baseline: 1.0756x; 1.0026x over previous
//
#include <hip/hip_runtime.h>
#include <math.h>

#define BATCH 8
#define CCH 20
#define THW 15000
#define HW 625
#define SSIDE 25

#define NKEY 15000
#define TPAD 15104      // 59*256, padded key dim
#define NKT 118         // ceil(15000/128) k-tiles of 128
#define NKC 15          // k-chunks (8 tiles each, last gets 6)

typedef __attribute__((ext_vector_type(8))) short bf16x8;
typedef __attribute__((ext_vector_type(4))) float f32x4;

// ---- ws layout (byte offsets) ----
#define YBF_OFF  0ULL
#define XA_OFF   640000ULL
#define XB_OFF   5760000ULL
#define WT0_OFF  10880000ULL
#define WT_OFF   11469824ULL
#define FMT_OFF  5760000ULL
#define FM32_OFF 13493248ULL
#define FQB_OFF  21226496ULL
#define PART_OFF XA_OFF   // bf16 partials: 8*5*15*128*48 B = 3.69 MB < 5.12 MB

// barrier WITHOUT vmcnt drain: waits only for LDS ops (lgkmcnt) so in-flight
// global prefetch loads survive the barrier. Safe because global loads target
// private VGPRs (no cross-wave visibility required).
#define BARRIER_LGKM() asm volatile("s_waitcnt lgkmcnt(0)\n\ts_barrier" ::: "memory")

__device__ __forceinline__ ushort f2bf(float x) {
    unsigned u = __float_as_uint(x);
    u = (u + 0x7FFFu + ((u >> 16) & 1u)) >> 16;
    return (ushort)u;
}
__device__ __forceinline__ float bf2f(ushort v) {
    return __uint_as_float(((unsigned)v) << 16);
}

// ===== prep: fm -> fmbT (t-major rows of 32 ch) + fmb32 (ch-major), bf16 =====
__global__ __launch_bounds__(256) void prep_fm(const float* __restrict__ fm,
                                               ushort* __restrict__ fmbT,
                                               ushort* __restrict__ fmb32) {
    __shared__ ushort sT2[256][34];
    const int tid = threadIdx.x;
    const int t0 = blockIdx.x * 256;
    const int b = blockIdx.y;
    const int t = t0 + tid;
    #pragma unroll 4
    for (int c = 0; c < CCH; c++) {
        float v = (t < NKEY) ? fm[((size_t)b * CCH + c) * THW + t] : 0.f;
        ushort h = f2bf(v);
        sT2[tid][c] = h;
        fmb32[((size_t)b * 32 + c) * TPAD + t] = h;
    }
    __syncthreads();
    const int g = tid >> 4, j = tid & 15;
    uint* dstb = (uint*)fmbT + ((size_t)b * TPAD + t0) * 16 + j;
    #pragma unroll
    for (int i = 0; i < 16; i++) {
        int r = g + 16 * i;
        uint v = 0;
        if (j < 10) v = *(const uint*)&sT2[r][2 * j];
        dstb[(size_t)r * 16] = v;
    }
}

// zero fmb32 channel rows 20..31
__global__ __launch_bounds__(256) void prep_fmz(ushort* __restrict__ fmb32) {
    int idx = blockIdx.x * 256 + threadIdx.x;
    if (idx >= 181248) return;             // 8*12*1888
    int t8 = idx % 1888;
    int rest = idx / 1888;
    int cz = rest % 12, b = rest / 12;
    uint4 z = make_uint4(0, 0, 0, 0);
    *(uint4*)(fmb32 + ((size_t)(b * 32 + 20 + cz)) * TPAD + t8 * 8) = z;
}

// fq -> fqb bf16 [b][640][32], scale 1/sqrt(512)*log2(e) folded
__global__ __launch_bounds__(256) void prep_fq(const float* __restrict__ fq,
                                               ushort* __restrict__ fqb) {
    int idx = blockIdx.x * 256 + threadIdx.x;
    if (idx >= BATCH * 640) return;
    int b = idx / 640, q = idx % 640;
    const float qscale = 1.4426950408889634f * 0.04419417382415922f;
    ushort* dst = fqb + (size_t)idx * 32;
    #pragma unroll 4
    for (int c = 0; c < CCH; c++) {
        float v = (q < HW) ? fq[((size_t)b * CCH + c) * HW + q] * qscale : 0.f;
        dst[c] = f2bf(v);
    }
    #pragma unroll
    for (int c = CCH; c < 32; c++) dst[c] = 0;
}

// ===== MFMA flash attention, 512-thread blocks (R12 version, unchanged) =====
__global__ __launch_bounds__(512) void attn_flash(const ushort* __restrict__ fmbT,
                                                  const ushort* __restrict__ fmb32,
                                                  const ushort* __restrict__ fqb,
                                                  char* __restrict__ part) {
    __shared__ __align__(16) ushort sP[8][2][16][136];
    const int tid = threadIdx.x;
    const int wave = tid >> 6, lane = tid & 63;
    const int q16 = lane & 15, quad = lane >> 4;
    const int qt = blockIdx.x * 2 + (wave >> 2);
    const int wq = wave & 3;
    const int kc = blockIdx.y, b = blockIdx.z;
    if (qt >= 5) return;

    bf16x8 Qf[2];
    #pragma unroll
    for (int nf = 0; nf < 2; nf++)
        Qf[nf] = *(const bf16x8*)(fqb + ((size_t)(b * 640 + qt * 128 + wq * 32 + nf * 16 + q16) << 5) + quad * 8);

    f32x4 O[2][2];
    #pragma unroll
    for (int nf = 0; nf < 2; nf++) { O[nf][0] = (f32x4)0.f; O[nf][1] = (f32x4)0.f; }
    float lp0 = 0.f, lp1 = 0.f;
    const f32x4 zz = (f32x4)0.f;

    const int kt0 = kc * 8;
    const int kt1 = (kt0 + 8 < NKT) ? kt0 + 8 : NKT;

    for (int kt = kt0; kt < kt1; kt++) {
        const int t0 = kt << 7;
        const bool tail = (t0 + 128 > NKEY);
        bf16x8 Ak[8], Av[8];
        #pragma unroll
        for (int m = 0; m < 8; m++)
            Ak[m] = *(const bf16x8*)(fmbT + ((size_t)(b * TPAD + t0 + m * 16 + q16) << 5) + quad * 8);
        #pragma unroll
        for (int mp = 0; mp < 4; mp++)
            #pragma unroll
            for (int cf = 0; cf < 2; cf++)
                Av[mp * 2 + cf] = *(const bf16x8*)(fmb32 + (size_t)(b * 32 + cf * 16 + q16) * TPAD + t0 + mp * 32 + quad * 8);

        f32x4 S[8][2];
        #pragma unroll
        for (int m = 0; m < 8; m++) {
            S[m][0] = __builtin_amdgcn_mfma_f32_16x16x32_bf16(Ak[m], Qf[0], zz, 0, 0, 0);
            S[m][1] = __builtin_amdgcn_mfma_f32_16x16x32_bf16(Ak[m], Qf[1], zz, 0, 0, 0);
        }

        #pragma unroll
        for (int nf = 0; nf < 2; nf++) {
            float lacc = 0.f;
            #pragma unroll
            for (int m = 0; m < 8; m++) {
                float p[4];
                #pragma unroll
                for (int i = 0; i < 4; i++) {
                    float v = __builtin_amdgcn_exp2f(S[m][nf][i]);
                    if (tail && (t0 + m * 16 + quad * 4 + i >= NKEY)) v = 0.f;
                    p[i] = v;
                }
                lacc += (p[0] + p[1]) + (p[2] + p[3]);
                uint pk0 = __builtin_amdgcn_perm(__float_as_uint(p[1]) + 0x8000u,
                                                 __float_as_uint(p[0]) + 0x8000u, 0x07060302u);
                uint pk1 = __builtin_amdgcn_perm(__float_as_uint(p[3]) + 0x8000u,
                                                 __float_as_uint(p[2]) + 0x8000u, 0x07060302u);
                uint* dst = (uint*)&sP[wave][nf][q16][m * 16 + quad * 4];
                dst[0] = pk0;
                dst[1] = pk1;
            }
            if (nf == 0) lp0 += lacc; else lp1 += lacc;
        }

        #pragma unroll
        for (int mp = 0; mp < 4; mp++) {
            bf16x8 Bp0 = *(const bf16x8*)&sP[wave][0][q16][mp * 32 + quad * 8];
            bf16x8 Bp1 = *(const bf16x8*)&sP[wave][1][q16][mp * 32 + quad * 8];
            O[0][0] = __builtin_amdgcn_mfma_f32_16x16x32_bf16(Av[mp * 2 + 0], Bp0, O[0][0], 0, 0, 0);
            O[0][1] = __builtin_amdgcn_mfma_f32_16x16x32_bf16(Av[mp * 2 + 1], Bp0, O[0][1], 0, 0, 0);
            O[1][0] = __builtin_amdgcn_mfma_f32_16x16x32_bf16(Av[mp * 2 + 0], Bp1, O[1][0], 0, 0, 0);
            O[1][1] = __builtin_amdgcn_mfma_f32_16x16x32_bf16(Av[mp * 2 + 1], Bp1, O[1][1], 0, 0, 0);
        }
    }

    lp0 += __shfl_xor(lp0, 16); lp0 += __shfl_xor(lp0, 32);
    lp1 += __shfl_xor(lp1, 16); lp1 += __shfl_xor(lp1, 32);

    #pragma unroll
    for (int nf = 0; nf < 2; nf++) {
        int ql = wq * 32 + nf * 16 + q16;
        size_t rec = ((((size_t)b * 5 + qt) * NKC + kc) * 128 + ql) * 48;
        uint2 pk;
        pk.x = (unsigned)f2bf(O[nf][0][0]) | ((unsigned)f2bf(O[nf][0][1]) << 16);
        pk.y = (unsigned)f2bf(O[nf][0][2]) | ((unsigned)f2bf(O[nf][0][3]) << 16);
        *(uint2*)(part + rec + quad * 8) = pk;
        if (quad == 0) {
            uint2 pk1;
            pk1.x = (unsigned)f2bf(O[nf][1][0]) | ((unsigned)f2bf(O[nf][1][1]) << 16);
            pk1.y = (unsigned)f2bf(O[nf][1][2]) | ((unsigned)f2bf(O[nf][1][3]) << 16);
            *(uint2*)(part + rec + 32) = pk1;
            *(float*)(part + rec + 40) = (nf == 0) ? lp0 : lp1;
        }
    }
}

// merge partials -> YBF bf16 NHWC [b][625][64]
__global__ __launch_bounds__(256) void attn_merge(const char* __restrict__ part,
                                                  const float* __restrict__ fq,
                                                  ushort* __restrict__ ybf) {
    int g = blockIdx.x * 256 + threadIdx.x;
    if (g >= BATCH * HW) return;
    int b = g / HW, q = g % HW;
    int qt = q >> 7, ql = q & 127;
    const char* pb = part + ((((size_t)b * 5 + qt) * NKC) * 128 + ql) * 48;
    float L = 0.f;
    float acc[CCH];
    #pragma unroll
    for (int c = 0; c < CCH; c++) acc[c] = 0.f;
    for (int kc = 0; kc < NKC; kc++) {
        const char* rec = pb + (size_t)kc * 128 * 48;
        L += *(const float*)(rec + 40);
        const ushort* av = (const ushort*)rec;
        #pragma unroll
        for (int c = 0; c < CCH; c++) acc[c] += bf2f(av[c]);
    }
    float inv = 1.f / L;
    ushort* yb = ybf + ((size_t)b * HW + q) * 64;
    #pragma unroll
    for (int c = 0; c < CCH; c++) yb[c] = f2bf(acc[c] * inv);
    #pragma unroll
    for (int c = 0; c < CCH; c++) yb[20 + c] = f2bf(fq[((size_t)b * CCH + c) * HW + q]);
    #pragma unroll
    for (int c = 40; c < 64; c++) yb[c] = 0;
}

// ================= weight prep =================
__global__ void prep_w0(const float* __restrict__ cw, const float* __restrict__ rw,
                        ushort* __restrict__ wt0) {
    int idx = blockIdx.x * 256 + threadIdx.x;
    if (idx >= 2 * 9 * 256 * 64) return;
    int ic = idx & 63;
    int oc = (idx >> 6) & 255;
    int t = idx >> 14;
    int kyx = t % 9;
    int br = t / 9;
    float v = 0.f;
    if (ic < 40) {
        const float* w = br ? rw : cw;
        v = w[((size_t)oc * 40 + ic) * 9 + kyx];
    }
    wt0[idx] = f2bf(v);
}

__global__ void prep_wk(const float* __restrict__ cw, const float* __restrict__ rw,
                        ushort* __restrict__ wt) {
    int idx = blockIdx.x * 256 + threadIdx.x;
    if (idx >= 6 * 2 * 9 * 256 * 256) return;
    int ic = idx & 255;
    int oc = (idx >> 8) & 255;
    int t = idx >> 16;
    int kyx = t % 9;
    t /= 9;
    int br = t & 1;
    int s = t >> 1;
    const float* w = br ? rw : cw;
    float v = w[(((size_t)s * 256 + oc) * 256 + ic) * 9 + kyx];
    wt[idx] = f2bf(v);
}

// ================= implicit-im2col GEMM conv, 64x64 tile, depth-2 + lgkm barrier ======
// R14 structure (two NAMED register sets, unroll-by-2, static indices, no spill)
// with the vmcnt-preserving barrier: prefetch loads issued for iter k+2 stay in
// flight across the iter-k barrier (the AITER "vmcnt never 0" pattern).
__global__ __launch_bounds__(256) void conv_gemm(
    const ushort* __restrict__ xin, int cin, int cshift, int in_shared, int relu_out,
    const ushort* __restrict__ wt, const float* __restrict__ bias_c,
    const float* __restrict__ bias_r, ushort* __restrict__ xout) {
    __shared__ ushort sA[2][64 * 64];
    __shared__ ushort sB[2][64 * 64];
    const int tid = threadIdx.x;
    const int lane = tid & 63;
    const int wave = tid >> 6;
    const int n16 = lane & 15, quad = lane >> 4;
    const int wm = wave & 1, wn = wave >> 1;
    const int ot = blockIdx.x & 3, nt = blockIdx.x >> 2;
    const int bb = blockIdx.y;
    const int oc0 = ot * 64;
    const ushort* wbr = wt + (size_t)(bb < 8 ? 0 : 1) * 9 * 256 * cin;
    const float* bias = (bb < 8) ? bias_c : bias_r;
    const ushort* inb = xin + (size_t)(in_shared ? (bb & 7) : bb) * HW * cin;

    const int srow = tid >> 2;
    const int sc = tid & 3;
    const ushort* aBase = wbr + (size_t)(oc0 + srow) * cin + sc * 8;
    const int p = nt * 64 + srow;
    const bool pok = (p < HW);
    const int pr = pok ? (p / 25) : 0;
    const int pc = pok ? (p % 25) : 0;
    const ushort* bBase = inb + (size_t)(pr * 25 + pc) * cin + sc * 8;
    const int swz0 = srow * 64 + ((sc ^ (srow & 7)) * 8);
    const int swz1 = srow * 64 + (((sc + 4) ^ (srow & 7)) * 8);

    const int NIT = 9 << cshift;
    const int cmask = (1 << cshift) - 1;

    // named register set A (even iterations) and B (odd iterations)
    uint4 raA0, raA1, rbA0, rbA1;
    uint4 raB0, raB1, rbB0, rbB1;
    auto loadA = [&](int it) {
        int kyx = it >> cshift;
        int ccc = it & cmask;
        int ky = (kyx >= 6) ? 2 : (kyx >= 3 ? 1 : 0);
        int kx = kyx - ky * 3;
        const ushort* aP = aBase + (size_t)(kyx * 256) * cin + ccc * 64;
        raA0 = *(const uint4*)(aP);
        raA1 = *(const uint4*)(aP + 32);
        int rr = pr + ky - 1, cc2 = pc + kx - 1;
        bool v = pok && ((unsigned)rr < 25u) && ((unsigned)cc2 < 25u);
        const ushort* bP = bBase + (ptrdiff_t)(((ky - 1) * 25 + (kx - 1)) * cin + ccc * 64);
        rbA0 = v ? *(const uint4*)(bP) : make_uint4(0, 0, 0, 0);
        rbA1 = v ? *(const uint4*)(bP + 32) : make_uint4(0, 0, 0, 0);
    };
    auto loadB = [&](int it) {
        int kyx = it >> cshift;
        int ccc = it & cmask;
        int ky = (kyx >= 6) ? 2 : (kyx >= 3 ? 1 : 0);
        int kx = kyx - ky * 3;
        const ushort* aP = aBase + (size_t)(kyx * 256) * cin + ccc * 64;
        raB0 = *(const uint4*)(aP);
        raB1 = *(const uint4*)(aP + 32);
        int rr = pr + ky - 1, cc2 = pc + kx - 1;
        bool v = pok && ((unsigned)rr < 25u) && ((unsigned)cc2 < 25u);
        const ushort* bP = bBase + (ptrdiff_t)(((ky - 1) * 25 + (kx - 1)) * cin + ccc * 64);
        rbB0 = v ? *(const uint4*)(bP) : make_uint4(0, 0, 0, 0);
        rbB1 = v ? *(const uint4*)(bP + 32) : make_uint4(0, 0, 0, 0);
    };
    auto stageA = [&](int bufi) {
        *(uint4*)&sA[bufi][swz0] = raA0; *(uint4*)&sA[bufi][swz1] = raA1;
        *(uint4*)&sB[bufi][swz0] = rbA0; *(uint4*)&sB[bufi][swz1] = rbA1;
    };
    auto stageB = [&](int bufi) {
        *(uint4*)&sA[bufi][swz0] = raB0; *(uint4*)&sA[bufi][swz1] = raB1;
        *(uint4*)&sB[bufi][swz0] = rbB0; *(uint4*)&sB[bufi][swz1] = rbB1;
    };

    f32x4 acc00 = (f32x4)0.f, acc01 = (f32x4)0.f;
    f32x4 acc10 = (f32x4)0.f, acc11 = (f32x4)0.f;

    const int arow0 = wm * 32 + n16;
    const int brow0 = wn * 32 + n16;
    const int h8 = n16 & 7;

    auto mfma_tile = [&](int bufi) {
        #pragma unroll
        for (int ks = 0; ks < 2; ks++) {
            const int swz = ((ks * 4 + quad) ^ h8) * 8;
            bf16x8 a0 = *(const bf16x8*)&sA[bufi][arow0 * 64 + swz];
            bf16x8 a1 = *(const bf16x8*)&sA[bufi][(arow0 + 16) * 64 + swz];
            bf16x8 b0 = *(const bf16x8*)&sB[bufi][brow0 * 64 + swz];
            bf16x8 b1 = *(const bf16x8*)&sB[bufi][(brow0 + 16) * 64 + swz];
            acc00 = __builtin_amdgcn_mfma_f32_16x16x32_bf16(a0, b0, acc00, 0, 0, 0);
            acc01 = __builtin_amdgcn_mfma_f32_16x16x32_bf16(a0, b1, acc01, 0, 0, 0);
            acc10 = __builtin_amdgcn_mfma_f32_16x16x32_bf16(a1, b0, acc10, 0, 0, 0);
            acc11 = __builtin_amdgcn_mfma_f32_16x16x32_bf16(a1, b1, acc11, 0, 0, 0);
        }
    };

    // prologue: iter 0 -> set A (staged), iter 1 -> set B (in regs)
    loadA(0);
    stageA(0);
    if (NIT > 1) loadB(1);
    BARRIER_LGKM();

    int buf = 0;
    for (int it = 0; it + 1 < NIT; it += 2) {
        // even iteration `it`
        if (it + 2 < NIT) loadA(it + 2);
        mfma_tile(buf);
        stageB(buf ^ 1);           // iter it+1 data; writes protected by prev barrier
        BARRIER_LGKM();            // drains LDS only; set-A prefetch stays in flight
        buf ^= 1;
        // odd iteration `it+1`
        if (it + 3 < NIT) loadB(it + 3);
        mfma_tile(buf);
        if (it + 2 < NIT) {
            stageA(buf ^ 1);       // iter it+2 data
            BARRIER_LGKM();
            buf ^= 1;
        }
    }
    if (NIT & 1) mfma_tile(buf);   // last (even-indexed) iteration, already staged

    f32x4 accs[2][2] = {{acc00, acc01}, {acc10, acc11}};
    #pragma unroll
    for (int mf = 0; mf < 2; mf++) {
        int ocb = oc0 + wm * 32 + mf * 16 + quad * 4;
        float4 bv = *(const float4*)(bias + ocb);
        #pragma unroll
        for (int nf = 0; nf < 2; nf++) {
            int pcol = nt * 64 + wn * 32 + nf * 16 + n16;
            if (pcol >= HW) continue;
            f32x4 a = accs[mf][nf];
            float v0 = a[0] + bv.x;
            float v1 = a[1] + bv.y;
            float v2 = a[2] + bv.z;
            float v3 = a[3] + bv.w;
            if (relu_out) {
                v0 = fmaxf(v0, 0.f); v1 = fmaxf(v1, 0.f);
                v2 = fmaxf(v2, 0.f); v3 = fmaxf(v3, 0.f);
            }
            uint2 st;
            st.x = (unsigned)f2bf(v0) | ((unsigned)f2bf(v1) << 16);
            st.y = (unsigned)f2bf(v2) | ((unsigned)f2bf(v3) << 16);
            *(uint2*)(&xout[((size_t)bb * HW + pcol) * 256 + ocb]) = st;
        }
    }
}

// ================= heads =================
__global__ __launch_bounds__(256) void heads(const ushort* __restrict__ X,
                                             const float* __restrict__ wcls, const float* __restrict__ bcls,
                                             const float* __restrict__ gcls, const float* __restrict__ becls,
                                             const float* __restrict__ wctr, const float* __restrict__ bctr,
                                             const float* __restrict__ gctr, const float* __restrict__ bectr,
                                             const float* __restrict__ woff, const float* __restrict__ boff,
                                             const float* __restrict__ goff, const float* __restrict__ beoff,
                                             const float* __restrict__ si, const float* __restrict__ bi,
                                             float* __restrict__ out) {
    int g = blockIdx.x * 256 + threadIdx.x;
    if (g >= BATCH * HW) return;
    int b = g / HW, p = g % HW;
    const ushort* fc = X + ((size_t)b * HW + p) * 256;
    const ushort* fr = X + ((size_t)(8 + b) * HW + p) * 256;
    float ac = 0.f, at = 0.f, a0 = 0.f, a1 = 0.f, a2 = 0.f, a3 = 0.f;
    for (int c0 = 0; c0 < 256; c0 += 8) {
        uint4 vc = *(const uint4*)(fc + c0);
        uint4 vr = *(const uint4*)(fr + c0);
        unsigned wc_[4] = {vc.x, vc.y, vc.z, vc.w};
        unsigned wr_[4] = {vr.x, vr.y, vr.z, vr.w};
        #pragma unroll
        for (int j = 0; j < 4; j++) {
            float cl = __uint_as_float(wc_[j] << 16);
            float ch = __uint_as_float(wc_[j] & 0xFFFF0000u);
            float rl = __uint_as_float(wr_[j] << 16);
            float rh = __uint_as_float(wr_[j] & 0xFFFF0000u);
            int c = c0 + j * 2;
            ac += wcls[c] * cl + wcls[c + 1] * ch;
            at += wctr[c] * cl + wctr[c + 1] * ch;
            a0 += woff[c] * rl + woff[c + 1] * rh;
            a1 += woff[256 + c] * rl + woff[256 + c + 1] * rh;
            a2 += woff[512 + c] * rl + woff[512 + c + 1] * rh;
            a3 += woff[768 + c] * rl + woff[768 + c + 1] * rh;
        }
    }
    const float bns = 1.f / sqrtf(1.f + 1e-5f);
    float cls = (ac + bcls[0]) * (gcls[0] * bns) + becls[0];
    float ctr = (at + bctr[0]) * (gctr[0] * bns) + bectr[0];
    float sv = si[0], bv = bi[0];
    float o0 = (a0 + boff[0]) * (goff[0] * bns) + beoff[0];
    float o1 = (a1 + boff[1]) * (goff[1] * bns) + beoff[1];
    float o2 = (a2 + boff[2]) * (goff[2] * bns) + beoff[2];
    float o3 = (a3 + boff[3]) * (goff[3] * bns) + beoff[3];
    float e0 = __expf(sv * o0 + bv) * 8.f;
    float e1 = __expf(sv * o1 + bv) * 8.f;
    float e2 = __expf(sv * o2 + bv) * 8.f;
    float e3 = __expf(sv * o3 + bv) * 8.f;
    float gx = 3.f + 8.f * (float)(p % SSIDE);
    float gy = 3.f + 8.f * (float)(p / SSIDE);
    out[g] = cls;
    out[BATCH * HW + g] = ctr;
    float* bbx = out + 2 * BATCH * HW + (size_t)g * 4;
    bbx[0] = gx - e0;
    bbx[1] = gy - e1;
    bbx[2] = gx + e2;
    bbx[3] = gy + e3;
}

extern "C" void kernel_launch(void* const* d_in, const int* in_sizes, int n_in,
                              void* d_out, int out_size, void* d_ws, size_t ws_size,
                              hipStream_t stream) {
    const float* fm     = (const float*)d_in[0];
    const float* fq     = (const float*)d_in[1];
    const float* cls1_w = (const float*)d_in[2];
    const float* cls1_b = (const float*)d_in[3];
    const float* clsk_w = (const float*)d_in[4];
    const float* clsk_b = (const float*)d_in[5];
    const float* reg1_w = (const float*)d_in[6];
    const float* reg1_b = (const float*)d_in[7];
    const float* regk_w = (const float*)d_in[8];
    const float* regk_b = (const float*)d_in[9];
    const float* w_cls  = (const float*)d_in[10];
    const float* b_cls  = (const float*)d_in[11];
    const float* g_cls  = (const float*)d_in[12];
    const float* be_cls = (const float*)d_in[13];
    const float* w_ctr  = (const float*)d_in[14];
    const float* b_ctr  = (const float*)d_in[15];
    const float* g_ctr  = (const float*)d_in[16];
    const float* be_ctr = (const float*)d_in[17];
    const float* w_off  = (const float*)d_in[18];
    const float* b_off  = (const float*)d_in[19];
    const float* g_off  = (const float*)d_in[20];
    const float* be_off = (const float*)d_in[21];
    const float* si     = (const float*)d_in[22];
    const float* bi     = (const float*)d_in[23];

    char* ws = (char*)d_ws;
    ushort* YBF  = (ushort*)(ws + YBF_OFF);
    ushort* XA   = (ushort*)(ws + XA_OFF);
    ushort* XB   = (ushort*)(ws + XB_OFF);
    ushort* WT0  = (ushort*)(ws + WT0_OFF);
    ushort* WT   = (ushort*)(ws + WT_OFF);
    ushort* FMT  = (ushort*)(ws + FMT_OFF);
    ushort* FM32 = (ushort*)(ws + FM32_OFF);
    ushort* FQB  = (ushort*)(ws + FQB_OFF);
    char*   PART = ws + PART_OFF;

    // --- attention (scratch aliases XB/WT region; consumed before those are written) ---
    prep_fm<<<dim3(59, 8), 256, 0, stream>>>(fm, FMT, FM32);
    prep_fmz<<<dim3(708), 256, 0, stream>>>(FM32);
    prep_fq<<<dim3(20), 256, 0, stream>>>(fq, FQB);
    attn_flash<<<dim3(3, NKC, 8), 512, 0, stream>>>(FMT, FM32, FQB, PART);
    attn_merge<<<dim3(20), 256, 0, stream>>>(PART, fq, YBF);

    // --- weight transposes (overwrite attention scratch) ---
    prep_w0<<<dim3((2 * 9 * 256 * 64 + 255) / 256), 256, 0, stream>>>(cls1_w, reg1_w, WT0);
    prep_wk<<<dim3((6 * 2 * 9 * 256 * 256 + 255) / 256), 256, 0, stream>>>(clsk_w, regk_w, WT);

    // --- conv tower: grid x = nt*4 + ot (40), y = bb (16) ---
    conv_gemm<<<dim3(40, 16), 256, 0, stream>>>(YBF, 64, 0, 1, 1, WT0, cls1_b, reg1_b, XA);

    ushort* cur = XA;
    ushort* nxt = XB;
    for (int s = 0; s < 6; s++) {
        int relu_out = (s < 5) ? 1 : 0;
        conv_gemm<<<dim3(40, 16), 256, 0, stream>>>(cur, 256, 2, 0, relu_out,
            WT + (size_t)s * 2 * 9 * 256 * 256,
            clsk_b + (size_t)s * 256, regk_b + (size_t)s * 256, nxt);
        ushort* tmp = cur; cur = nxt; nxt = tmp;
    }

    heads<<<dim3(20), 256, 0, stream>>>(cur, w_cls, b_cls, g_cls, be_cls,
                                        w_ctr, b_ctr, g_ctr, be_ctr,
                                        w_off, b_off, g_off, be_off, si, bi,
                                        (float*)d_out);
}